// Round 3
// baseline (2248.765 us; speedup 1.0000x reference)
//
#include <hip/hip_runtime.h>
#include <hip/hip_bf16.h>
#include <cstdint>

// StructuredSlotCommunication: qkv-proj GEMM -> tiny masked attention (S=3) ->
// out-proj GEMM -> residual+LayerNorm.  bf16 MFMA for both GEMMs (threshold is
// bf16-floor), f32 accumulate everywhere.
//
// B=32768 S=3 H=1024 NH=16 HD=64; M = B*S = 98304 rows, K = 1024.
//
// ws layout (209,715,200 B needed):
//   [0)            A_bf16 [98304][1024]   -- slots cast to bf16; chunk-wise
//                                            REUSED as ctx_bf16 after consumed
//   [201326592)    W1_bf16 [3072][1024]
//   [207618048)    W2_bf16 [1024][1024]
// d_out reused as scratch: qkv bf16 chunk (302 MB) then attn_out f32 (402 MB).

#define DEVI __device__ __forceinline__

typedef __attribute__((ext_vector_type(8))) short short8;
typedef __attribute__((ext_vector_type(4))) float f32x4;

DEVI unsigned short f2bf(float f) {
  unsigned u = __builtin_bit_cast(unsigned, f);
  u += 0x7FFFu + ((u >> 16) & 1u);          // round-to-nearest-even
  return (unsigned short)(u >> 16);
}
DEVI float bf2f(unsigned short s) {
  unsigned u = ((unsigned)s) << 16;
  return __builtin_bit_cast(float, u);
}
DEVI float wave_sum(float x) {
  #pragma unroll
  for (int o = 32; o; o >>= 1) x += __shfl_xor(x, o, 64);
  return x;
}
DEVI void gload_lds16(const void* g, void* l) {
  __builtin_amdgcn_global_load_lds(
      (const __attribute__((address_space(1))) unsigned int*)g,
      (__attribute__((address_space(3))) unsigned int*)l, 16, 0, 0);
}

// ---------------------------------------------------------------- cvt f32->bf16
__global__ __launch_bounds__(256) void cvt_bf16_kernel(
    const float* __restrict__ in, short* __restrict__ out, int n8) {
  int i = blockIdx.x * 256 + threadIdx.x;
  if (i >= n8) return;
  const float4* p = (const float4*)in;
  float4 u = p[(size_t)i * 2], w = p[(size_t)i * 2 + 1];
  short8 r;
  r[0] = (short)f2bf(u.x); r[1] = (short)f2bf(u.y);
  r[2] = (short)f2bf(u.z); r[3] = (short)f2bf(u.w);
  r[4] = (short)f2bf(w.x); r[5] = (short)f2bf(w.y);
  r[6] = (short)f2bf(w.z); r[7] = (short)f2bf(w.w);
  *(short8*)(out + (size_t)i * 8) = r;
}

// ------------------------------------------------------------------- GEMM (B^T)
// C[m][n] = sum_k A[m][k] * Bw[n][k] + bias[n].  K=1024 fixed.
// m97 structure: 128x128 tile, BK=32, 256 threads (4 waves, 2x2 wave grid),
// global_load_lds dwordx4 staging, 2 barriers per K-step, mfma 16x16x32 bf16.
template <typename OT>
__global__ __launch_bounds__(256) void gemm_bt_kernel(
    const short* __restrict__ A, const short* __restrict__ Bw,
    const float* __restrict__ bias, OT* __restrict__ C, int N) {
  constexpr int K = 1024;
  __shared__ __align__(16) short As[128 * 32];
  __shared__ __align__(16) short Bs[128 * 32];

  const int NT = N >> 7;
  const int mt = blockIdx.x / NT, nt = blockIdx.x % NT;
  const int m0 = mt * 128, n0 = nt * 128;
  const int t = threadIdx.x;
  const int lane = t & 63, w = t >> 6;
  const int wr = w >> 1, wc = w & 1;   // 2x2 waves, each owns 64x64

  const short* aG = A + (size_t)m0 * K;
  const short* bG = Bw + (size_t)n0 * K;

  f32x4 acc[4][4] = {};

  for (int k0 = 0; k0 < K; k0 += 32) {
    // stage 128x32 bf16 tiles of A and B.  chunk c covers LDS bytes [c*16,+16):
    // row = c>>2, col8 = (c&3)*8 -> lane-contiguous LDS dest (linear layout).
    #pragma unroll
    for (int i = 0; i < 2; ++i) {
      int c = t + i * 256;
      int row = c >> 2, col = (c & 3) << 3;
      gload_lds16(aG + (size_t)row * K + k0 + col, &As[c * 8]);
      gload_lds16(bG + (size_t)row * K + k0 + col, &Bs[c * 8]);
    }
    __syncthreads();   // drains vmcnt -> LDS tiles ready

    short8 af[4], bf[4];
    #pragma unroll
    for (int fm = 0; fm < 4; ++fm)
      af[fm] = *(const short8*)&As[(wr * 64 + fm * 16 + (lane & 15)) * 32 + (lane >> 4) * 8];
    #pragma unroll
    for (int fn = 0; fn < 4; ++fn)
      bf[fn] = *(const short8*)&Bs[(wc * 64 + fn * 16 + (lane & 15)) * 32 + (lane >> 4) * 8];
    #pragma unroll
    for (int fm = 0; fm < 4; ++fm)
      #pragma unroll
      for (int fn = 0; fn < 4; ++fn)
        acc[fm][fn] = __builtin_amdgcn_mfma_f32_16x16x32_bf16(af[fm], bf[fn], acc[fm][fn], 0, 0, 0);
    __syncthreads();   // protect LDS before next-iter staging
  }

  // epilogue: D row=(lane>>4)*4+r, col=lane&15 (m89-verified layout)
  #pragma unroll
  for (int fm = 0; fm < 4; ++fm) {
    #pragma unroll
    for (int fn = 0; fn < 4; ++fn) {
      int col = n0 + wc * 64 + fn * 16 + (lane & 15);
      float bv = bias[col];
      #pragma unroll
      for (int r = 0; r < 4; ++r) {
        int row = m0 + wr * 64 + fm * 16 + (lane >> 4) * 4 + r;
        float v = acc[fm][fn][r] + bv;
        if constexpr (sizeof(OT) == 2)
          C[(size_t)row * N + col] = (OT)f2bf(v);
        else
          C[(size_t)row * N + col] = v;
      }
    }
  }
}

// ------------------------------------------------------------------- attention
// one wave per (batch, head); lane = head-dim.  qkv rows local to chunk.
__global__ __launch_bounds__(256) void attn_kernel(
    const short* __restrict__ qkv,   // [nb*3][3072] bf16
    short* __restrict__ ctx,         // [nb*3][1024] bf16
    int nb) {
  int wid = blockIdx.x * 4 + (threadIdx.x >> 6);
  if (wid >= nb * 16) return;
  int lane = threadIdx.x & 63;
  int b = wid >> 4, h = wid & 15;
  const size_t row0 = (size_t)b * 3 * 3072;
  const int cq = h * 64 + lane;

  float q[3], k[3], v[3];
  #pragma unroll
  for (int s = 0; s < 3; ++s) {
    q[s] = bf2f((unsigned short)qkv[row0 + s * 3072 + cq]);
    k[s] = bf2f((unsigned short)qkv[row0 + s * 3072 + 1024 + cq]);
    v[s] = bf2f((unsigned short)qkv[row0 + s * 3072 + 2048 + cq]);
  }

  float sc[3][3];
  #pragma unroll
  for (int i = 0; i < 3; ++i)
    #pragma unroll
    for (int j = 0; j < 3; ++j) {
      float x = q[i] * k[j];
      x = wave_sum(x);
      sc[i][j] = x * 0.125f;          // 1/sqrt(64)
    }
  // transitive mask: q0 can't see k1; q1 can't see k0
  sc[0][1] = -1e9f;
  sc[1][0] = -1e9f;

  #pragma unroll
  for (int i = 0; i < 3; ++i) {
    float m = fmaxf(fmaxf(sc[i][0], sc[i][1]), sc[i][2]);
    float p0 = expf(sc[i][0] - m), p1 = expf(sc[i][1] - m), p2 = expf(sc[i][2] - m);
    float inv = 1.0f / (p0 + p1 + p2);
    float o = (p0 * v[0] + p1 * v[1] + p2 * v[2]) * inv;
    ctx[((size_t)b * 3 + i) * 1024 + cq] = (short)f2bf(o);
  }
}

// --------------------------------------------------------- residual + layernorm
// one block per row; x = slots + attn_out (in-place on d_out).
__global__ __launch_bounds__(256) void ln_kernel(
    const float* __restrict__ slots, float* __restrict__ io,
    const float* __restrict__ gamma, const float* __restrict__ beta) {
  __shared__ float sm1[4], sm2[4];
  const size_t row = blockIdx.x;
  const int t = threadIdx.x, lane = t & 63, w = t >> 6;
  const float4* sp = (const float4*)(slots + row * 1024);
  float4* op = (float4*)(io + row * 1024);

  float4 a = sp[t], b = op[t];
  float x0 = a.x + b.x, x1 = a.y + b.y, x2 = a.z + b.z, x3 = a.w + b.w;

  float s = wave_sum(x0 + x1 + x2 + x3);
  if (lane == 0) sm1[w] = s;
  __syncthreads();
  float mu = (sm1[0] + sm1[1] + sm1[2] + sm1[3]) * (1.0f / 1024.0f);

  float d0 = x0 - mu, d1 = x1 - mu, d2 = x2 - mu, d3 = x3 - mu;
  float ss = wave_sum(d0 * d0 + d1 * d1 + d2 * d2 + d3 * d3);
  if (lane == 0) sm2[w] = ss;
  __syncthreads();
  float var = (sm2[0] + sm2[1] + sm2[2] + sm2[3]) * (1.0f / 1024.0f);
  float rs = rsqrtf(var + 1e-5f);

  float4 g = ((const float4*)gamma)[t], be = ((const float4*)beta)[t];
  float4 o;
  o.x = d0 * rs * g.x + be.x;
  o.y = d1 * rs * g.y + be.y;
  o.z = d2 * rs * g.z + be.z;
  o.w = d3 * rs * g.w + be.w;
  op[t] = o;
}

// ------------------------------------------------------------------------ host
extern "C" void kernel_launch(void* const* d_in, const int* in_sizes, int n_in,
                              void* d_out, int out_size, void* d_ws, size_t ws_size,
                              hipStream_t stream) {
  const float* slots = (const float*)d_in[0];
  const float* w_in  = (const float*)d_in[1];
  const float* b_in  = (const float*)d_in[2];
  const float* w_out = (const float*)d_in[3];
  const float* b_out = (const float*)d_in[4];
  const float* gamma = (const float*)d_in[5];
  const float* beta  = (const float*)d_in[6];

  constexpr size_t M = 98304;          // B*S
  constexpr size_t SZ_A = M * 1024 * 2;
  char* ws = (char*)d_ws;
  short* A  = (short*)ws;                            // slots bf16 / later ctx bf16
  short* W1 = (short*)(ws + SZ_A);                   // [3072][1024]
  short* W2 = (short*)(ws + SZ_A + 6291456);         // [1024][1024]
  short* CT = A;                                     // ctx aliases A (chunk-safe)
  short* qkvb = (short*)d_out;                       // qkv chunk scratch (302MB)
  float* aout = (float*)d_out;                       // attn_out f32

  // f32 -> bf16 casts
  cvt_bf16_kernel<<<49152, 256, 0, stream>>>(slots, A, 12582912);
  cvt_bf16_kernel<<<1536, 256, 0, stream>>>(w_in, W1, 393216);
  cvt_bf16_kernel<<<512, 256, 0, stream>>>(w_out, W2, 131072);

  // 2 chunks of 16384 batches (49152 rows): qkv GEMM -> attention
  constexpr int ROWS_C = 49152;
  for (int c = 0; c < 2; ++c) {
    const short* Ac = A + (size_t)c * ROWS_C * 1024;
    gemm_bt_kernel<short><<<(ROWS_C / 128) * (3072 / 128), 256, 0, stream>>>(
        Ac, W1, b_in, qkvb, 3072);
    attn_kernel<<<16384 * 16 / 4, 256, 0, stream>>>(
        qkvb, CT + (size_t)c * ROWS_C * 1024, 16384);
  }

  // out projection (+out_b) -> attn_out f32 in d_out
  gemm_bt_kernel<float><<<(M / 128) * (1024 / 128), 256, 0, stream>>>(
      CT, W2, b_out, aout, 1024);

  // residual + layernorm, in place on d_out
  ln_kernel<<<M, 256, 0, stream>>>(slots, aout, gamma, beta);
}

// Round 9
// 2066.055 us; speedup vs baseline: 1.0884x; 1.0884x over previous
//
#include <hip/hip_runtime.h>
#include <hip/hip_bf16.h>
#include <cstdint>

// StructuredSlotCommunication: qkv-proj GEMM -> tiny masked attention (S=3) ->
// out-proj GEMM -> residual+LayerNorm.  bf16 MFMA for both GEMMs (threshold is
// bf16-floor), f32 accumulate everywhere.
//
// B=32768 S=3 H=1024 NH=16 HD=64; M = B*S = 98304 rows, K = 1024.
//
// R4 changes vs R3 (baseline 2249 us, absmax 0.03125):
//  - attn: 8 heads/wave, short8 vector loads (was scalar 2B + 54 shuffles);
//    R3 attn was latency-bound (rocprof replay showed it pathologically).
//  - T1 XCD-aware block swizzle on both GEMMs (FETCH_SIZE was 4x ideal:
//    A-panels re-fetched per XCD; stage latency is on the 2-phase crit path).
//
// ws layout:
//   [0)            A_bf16 [98304][1024]   -- slots cast to bf16; chunk-wise
//                                            REUSED as ctx_bf16 after consumed
//   [201326592)    W1_bf16 [3072][1024]
//   [207618048)    W2_bf16 [1024][1024]
// d_out reused as scratch: qkv bf16 chunk (302 MB) then attn_out f32 (402 MB).

#define DEVI __device__ __forceinline__

typedef __attribute__((ext_vector_type(8))) short short8;
typedef __attribute__((ext_vector_type(4))) float f32x4;

DEVI unsigned short f2bf(float f) {
  unsigned u = __builtin_bit_cast(unsigned, f);
  u += 0x7FFFu + ((u >> 16) & 1u);          // round-to-nearest-even
  return (unsigned short)(u >> 16);
}
DEVI float bf2f(unsigned short s) {
  unsigned u = ((unsigned)s) << 16;
  return __builtin_bit_cast(float, u);
}
DEVI float wave_sum(float x) {
  #pragma unroll
  for (int o = 32; o; o >>= 1) x += __shfl_xor(x, o, 64);
  return x;
}
DEVI void gload_lds16(const void* g, void* l) {
  __builtin_amdgcn_global_load_lds(
      (const __attribute__((address_space(1))) unsigned int*)g,
      (__attribute__((address_space(3))) unsigned int*)l, 16, 0, 0);
}

// ---------------------------------------------------------------- cvt f32->bf16
__global__ __launch_bounds__(256) void cvt_bf16_kernel(
    const float* __restrict__ in, short* __restrict__ out, int n8) {
  int i = blockIdx.x * 256 + threadIdx.x;
  if (i >= n8) return;
  const float4* p = (const float4*)in;
  float4 u = p[(size_t)i * 2], w = p[(size_t)i * 2 + 1];
  short8 r;
  r[0] = (short)f2bf(u.x); r[1] = (short)f2bf(u.y);
  r[2] = (short)f2bf(u.z); r[3] = (short)f2bf(u.w);
  r[4] = (short)f2bf(w.x); r[5] = (short)f2bf(w.y);
  r[6] = (short)f2bf(w.z); r[7] = (short)f2bf(w.w);
  *(short8*)(out + (size_t)i * 8) = r;
}

// ------------------------------------------------------------------- GEMM (B^T)
// C[m][n] = sum_k A[m][k] * Bw[n][k] + bias[n].  K=1024 fixed.
// m97 structure: 128x128 tile, BK=32, 256 threads (4 waves, 2x2 wave grid),
// global_load_lds dwordx4 staging, 2 barriers per K-step, mfma 16x16x32 bf16.
// T1: XCD-aware bijective block swizzle (grid % 8 == 0 for all our launches).
template <typename OT>
__global__ __launch_bounds__(256) void gemm_bt_kernel(
    const short* __restrict__ A, const short* __restrict__ Bw,
    const float* __restrict__ bias, OT* __restrict__ C, int N) {
  constexpr int K = 1024;
  __shared__ __align__(16) short As[128 * 32];
  __shared__ __align__(16) short Bs[128 * 32];

  const int NT = N >> 7;
  // T1: consecutive swz-ids land on the same XCD -> A-panel reuse in XCD L2.
  const int nwg = gridDim.x;
  const int swz = (blockIdx.x & 7) * (nwg >> 3) + (blockIdx.x >> 3);
  const int mt = swz / NT, nt = swz % NT;
  const int m0 = mt * 128, n0 = nt * 128;
  const int t = threadIdx.x;
  const int lane = t & 63, w = t >> 6;
  const int wr = w >> 1, wc = w & 1;   // 2x2 waves, each owns 64x64

  const short* aG = A + (size_t)m0 * K;
  const short* bG = Bw + (size_t)n0 * K;

  f32x4 acc[4][4] = {};

  for (int k0 = 0; k0 < K; k0 += 32) {
    // stage 128x32 bf16 tiles of A and B.  chunk c covers LDS bytes [c*16,+16):
    // row = c>>2, col8 = (c&3)*8 -> lane-contiguous LDS dest (linear layout).
    #pragma unroll
    for (int i = 0; i < 2; ++i) {
      int c = t + i * 256;
      int row = c >> 2, col = (c & 3) << 3;
      gload_lds16(aG + (size_t)row * K + k0 + col, &As[c * 8]);
      gload_lds16(bG + (size_t)row * K + k0 + col, &Bs[c * 8]);
    }
    __syncthreads();   // drains vmcnt -> LDS tiles ready

    short8 af[4], bf[4];
    #pragma unroll
    for (int fm = 0; fm < 4; ++fm)
      af[fm] = *(const short8*)&As[(wr * 64 + fm * 16 + (lane & 15)) * 32 + (lane >> 4) * 8];
    #pragma unroll
    for (int fn = 0; fn < 4; ++fn)
      bf[fn] = *(const short8*)&Bs[(wc * 64 + fn * 16 + (lane & 15)) * 32 + (lane >> 4) * 8];
    #pragma unroll
    for (int fm = 0; fm < 4; ++fm)
      #pragma unroll
      for (int fn = 0; fn < 4; ++fn)
        acc[fm][fn] = __builtin_amdgcn_mfma_f32_16x16x32_bf16(af[fm], bf[fn], acc[fm][fn], 0, 0, 0);
    __syncthreads();   // protect LDS before next-iter staging
  }

  // epilogue: D row=(lane>>4)*4+r, col=lane&15 (m89-verified layout)
  #pragma unroll
  for (int fm = 0; fm < 4; ++fm) {
    #pragma unroll
    for (int fn = 0; fn < 4; ++fn) {
      int col = n0 + wc * 64 + fn * 16 + (lane & 15);
      float bv = bias[col];
      #pragma unroll
      for (int r = 0; r < 4; ++r) {
        int row = m0 + wr * 64 + fm * 16 + (lane >> 4) * 4 + r;
        float v = acc[fm][fn][r] + bv;
        if constexpr (sizeof(OT) == 2)
          C[(size_t)row * N + col] = (OT)f2bf(v);
        else
          C[(size_t)row * N + col] = v;
      }
    }
  }
}

// ------------------------------------------------------------------- attention
// one wave per (batch, 8-head group); lane l covers head h0+(l>>3), dims
// [(l&7)*8, +8).  Column within the 512-wide head-group = 8*l, so every
// wave-level load/store is a contiguous 1 KB short8 access.  Reductions are
// 3-step shfl_xor within aligned 8-lane groups.
__global__ __launch_bounds__(256) void attn_kernel(
    const short* __restrict__ qkv,   // [nb*3][3072] bf16
    short* __restrict__ ctx,         // [nb*3][1024] bf16
    int nb) {
  const int wid = blockIdx.x * 4 + (threadIdx.x >> 6);   // 2 waves per batch
  const int lane = threadIdx.x & 63;
  const int b = wid >> 1;
  const int h8 = (wid & 1) * 512;          // head-group column offset
  const size_t base = (size_t)b * 3 * 3072 + h8 + lane * 8;

  float q[3][8], k[3][8], v[3][8];
  #pragma unroll
  for (int s = 0; s < 3; ++s) {
    short8 qs = *(const short8*)(qkv + base + s * 3072);
    short8 ks = *(const short8*)(qkv + base + s * 3072 + 1024);
    short8 vs = *(const short8*)(qkv + base + s * 3072 + 2048);
    #pragma unroll
    for (int d = 0; d < 8; ++d) {
      q[s][d] = bf2f((unsigned short)qs[d]);
      k[s][d] = bf2f((unsigned short)ks[d]);
      v[s][d] = bf2f((unsigned short)vs[d]);
    }
  }

  float sc[3][3];
  #pragma unroll
  for (int i = 0; i < 3; ++i)
    #pragma unroll
    for (int j = 0; j < 3; ++j) {
      float p = 0.0f;
      #pragma unroll
      for (int d = 0; d < 8; ++d) p += q[i][d] * k[j][d];
      p += __shfl_xor(p, 1, 64);
      p += __shfl_xor(p, 2, 64);
      p += __shfl_xor(p, 4, 64);
      sc[i][j] = p * 0.125f;          // 1/sqrt(64)
    }
  // transitive mask: q0 can't see k1; q1 can't see k0
  sc[0][1] = -1e9f;
  sc[1][0] = -1e9f;

  #pragma unroll
  for (int i = 0; i < 3; ++i) {
    float m = fmaxf(fmaxf(sc[i][0], sc[i][1]), sc[i][2]);
    float p0 = expf(sc[i][0] - m), p1 = expf(sc[i][1] - m), p2 = expf(sc[i][2] - m);
    float inv = 1.0f / (p0 + p1 + p2);
    short8 r;
    #pragma unroll
    for (int d = 0; d < 8; ++d) {
      float o = (p0 * v[0][d] + p1 * v[1][d] + p2 * v[2][d]) * inv;
      r[d] = (short)f2bf(o);
    }
    *(short8*)(ctx + (size_t)(b * 3 + i) * 1024 + h8 + lane * 8) = r;
  }
}

// --------------------------------------------------------- residual + layernorm
// one block per row; x = slots + attn_out (in-place on d_out).
__global__ __launch_bounds__(256) void ln_kernel(
    const float* __restrict__ slots, float* __restrict__ io,
    const float* __restrict__ gamma, const float* __restrict__ beta) {
  __shared__ float sm1[4], sm2[4];
  const size_t row = blockIdx.x;
  const int t = threadIdx.x, lane = t & 63, w = t >> 6;
  const float4* sp = (const float4*)(slots + row * 1024);
  float4* op = (float4*)(io + row * 1024);

  float4 a = sp[t], b = op[t];
  float x0 = a.x + b.x, x1 = a.y + b.y, x2 = a.z + b.z, x3 = a.w + b.w;

  float s = wave_sum(x0 + x1 + x2 + x3);
  if (lane == 0) sm1[w] = s;
  __syncthreads();
  float mu = (sm1[0] + sm1[1] + sm1[2] + sm1[3]) * (1.0f / 1024.0f);

  float d0 = x0 - mu, d1 = x1 - mu, d2 = x2 - mu, d3 = x3 - mu;
  float ss = wave_sum(d0 * d0 + d1 * d1 + d2 * d2 + d3 * d3);
  if (lane == 0) sm2[w] = ss;
  __syncthreads();
  float var = (sm2[0] + sm2[1] + sm2[2] + sm2[3]) * (1.0f / 1024.0f);
  float rs = rsqrtf(var + 1e-5f);

  float4 g = ((const float4*)gamma)[t], be = ((const float4*)beta)[t];
  float4 o;
  o.x = d0 * rs * g.x + be.x;
  o.y = d1 * rs * g.y + be.y;
  o.z = d2 * rs * g.z + be.z;
  o.w = d3 * rs * g.w + be.w;
  op[t] = o;
}

// ------------------------------------------------------------------------ host
extern "C" void kernel_launch(void* const* d_in, const int* in_sizes, int n_in,
                              void* d_out, int out_size, void* d_ws, size_t ws_size,
                              hipStream_t stream) {
  const float* slots = (const float*)d_in[0];
  const float* w_in  = (const float*)d_in[1];
  const float* b_in  = (const float*)d_in[2];
  const float* w_out = (const float*)d_in[3];
  const float* b_out = (const float*)d_in[4];
  const float* gamma = (const float*)d_in[5];
  const float* beta  = (const float*)d_in[6];

  constexpr size_t M = 98304;          // B*S
  constexpr size_t SZ_A = M * 1024 * 2;
  char* ws = (char*)d_ws;
  short* A  = (short*)ws;                            // slots bf16 / later ctx bf16
  short* W1 = (short*)(ws + SZ_A);                   // [3072][1024]
  short* W2 = (short*)(ws + SZ_A + 6291456);         // [1024][1024]
  short* CT = A;                                     // ctx aliases A (chunk-safe)
  short* qkvb = (short*)d_out;                       // qkv chunk scratch (302MB)
  float* aout = (float*)d_out;                       // attn_out f32

  // f32 -> bf16 casts
  cvt_bf16_kernel<<<49152, 256, 0, stream>>>(slots, A, 12582912);
  cvt_bf16_kernel<<<1536, 256, 0, stream>>>(w_in, W1, 393216);
  cvt_bf16_kernel<<<512, 256, 0, stream>>>(w_out, W2, 131072);

  // 2 chunks of 16384 batches (49152 rows): qkv GEMM -> attention
  constexpr int ROWS_C = 49152;
  for (int c = 0; c < 2; ++c) {
    const short* Ac = A + (size_t)c * ROWS_C * 1024;
    gemm_bt_kernel<short><<<(ROWS_C / 128) * (3072 / 128), 256, 0, stream>>>(
        Ac, W1, b_in, qkvb, 3072);
    attn_kernel<<<16384 / 2, 256, 0, stream>>>(
        qkvb, CT + (size_t)c * ROWS_C * 1024, 16384);
  }

  // out projection (+out_b) -> attn_out f32 in d_out
  gemm_bt_kernel<float><<<(M / 128) * (1024 / 128), 256, 0, stream>>>(
      CT, W2, b_out, aout, 1024);

  // residual + layernorm, in place on d_out
  ln_kernel<<<M, 256, 0, stream>>>(slots, aout, gamma, beta);
}